// Round 1
// baseline (2981.919 us; speedup 1.0000x reference)
//
#include <hip/hip_runtime.h>
#include <math.h>

#define Bsz 128
#define Tsz 512
#define Isz 2
#define Hsz 1024
#define NM  8
#define MS  128
#define NTHREADS 512
#define NWAVES   (NTHREADS / 64)

// ---------------------------------------------------------------------------
// Transpose W_hh (1024x1024) into workspace: WT[j*H + i] = W[i*H + j]
// ---------------------------------------------------------------------------
__global__ __launch_bounds__(256)
void transpose_whh(const float* __restrict__ W, float* __restrict__ WT) {
    __shared__ float tile[32][33];                 // +1 pad: no bank conflicts
    const int bx = blockIdx.x * 32;                // col tile
    const int by = blockIdx.y * 32;                // row tile
    const int tx = threadIdx.x;                    // 0..31
    const int ty = threadIdx.y;                    // 0..7
    #pragma unroll
    for (int k = 0; k < 32; k += 8)
        tile[ty + k][tx] = W[(size_t)(by + ty + k) * Hsz + bx + tx];
    __syncthreads();
    #pragma unroll
    for (int k = 0; k < 32; k += 8)
        WT[(size_t)(bx + ty + k) * Hsz + by + tx] = tile[tx][ty + k];
}

// ---------------------------------------------------------------------------
// Persistent per-batch-element Clockwork RNN kernel.
//   grid = 128 blocks (one per b), 512 threads.
// LDS state: h[1024], S[r*8+c][128] cached partial matvecs, output scratch.
// ---------------------------------------------------------------------------
__global__ __launch_bounds__(NTHREADS)
void cwrnn_kernel(const float* __restrict__ x,      // [B, T+1, 2, 1]
                  const float* __restrict__ W_ih,   // [H, 2]
                  const float* __restrict__ fc_w,   // [2, H]
                  const float* __restrict__ fc_b,   // [2]
                  const float* __restrict__ enc_w,  // [H, 2]
                  const float* __restrict__ WT,     // [H, H] = W_hh transposed
                  float* __restrict__ out)          // [B, T, 2]
{
    __shared__ float h_s[Hsz];
    __shared__ float S[NM * NM][MS];        // only r<=c slots used
    __shared__ float ored[NWAVES * 2];

    const int b    = blockIdx.x;
    const int tid  = threadIdx.x;
    const int lane = tid & 63;
    const int wave = tid >> 6;

    const float* xb = x + (size_t)b * (Tsz + 1) * Isz;

    // ---- h0 = x[:,0] @ enc_w.T ----
    {
        const float x00 = xb[0], x01 = xb[1];
        for (int i = tid; i < Hsz; i += NTHREADS)
            h_s[i] = x00 * enc_w[i * 2] + x01 * enc_w[i * 2 + 1];
    }
    __syncthreads();

    // ---- pair refresh: S[r][c][i] = sum_j W[r*128+i][c*128+j] * h[c*128+j]
    //      one wave per pair; lane covers rows 2*lane, 2*lane+1 (coalesced
    //      float2 loads from WT; h value is an LDS broadcast read).
    auto refresh_pair = [&](int r, int c) {
        const float* wp = WT + (size_t)(c * MS) * Hsz + r * MS + 2 * lane;
        const float* hp = h_s + c * MS;
        float a0 = 0.f, a1 = 0.f;
        #pragma unroll 4
        for (int j = 0; j < MS; j += 4) {
            float4 hv = *(const float4*)(hp + j);
            float2 w0 = *(const float2*)(wp + (size_t)(j + 0) * Hsz);
            float2 w1 = *(const float2*)(wp + (size_t)(j + 1) * Hsz);
            float2 w2 = *(const float2*)(wp + (size_t)(j + 2) * Hsz);
            float2 w3 = *(const float2*)(wp + (size_t)(j + 3) * Hsz);
            a0 += w0.x * hv.x; a1 += w0.y * hv.x;
            a0 += w1.x * hv.y; a1 += w1.y * hv.y;
            a0 += w2.x * hv.z; a1 += w2.y * hv.z;
            a0 += w3.x * hv.w; a1 += w3.y * hv.w;
        }
        S[r * 8 + c][2 * lane]     = a0;
        S[r * 8 + c][2 * lane + 1] = a1;
    };

    // decode k-th pair (c-major triangular: (0,0),(0,1),(1,1),(0,2),...)
    auto pair_rc = [&](int k, int& r, int& c) {
        c = (int)((sqrtf((float)(8 * k + 1)) - 1.0f) * 0.5f);
        r = k - c * (c + 1) / 2;
    };

    // ---- initial refresh of all 36 pairs from h0 ----
    for (int k = wave; k < 36; k += NWAVES) {
        int r, c; pair_rc(k, r, c);
        refresh_pair(r, c);
    }
    __syncthreads();

    float* outb = out + (size_t)b * Tsz * Isz;

    for (int t = 0; t < Tsz; ++t) {
        // active modules are 0..A  (module m active iff t % 2^m == 0)
        const int A = (t == 0) ? 7 : min(__ffs(t) - 1, 7);
        const int nrows = (A + 1) * MS;
        const float xt0 = xb[(t + 1) * 2];
        const float xt1 = xb[(t + 1) * 2 + 1];

        // ---- 1. cand + h update for the active prefix of rows ----
        for (int g = tid; g < nrows; g += NTHREADS) {
            const int r  = g >> 7;
            const int il = g & 127;
            float pre = xt0 * W_ih[g * 2] + xt1 * W_ih[g * 2 + 1];
            for (int c = r; c < NM; ++c)
                pre += S[r * 8 + c][il];
            h_s[g] = tanhf(pre);
        }
        __syncthreads();

        // ---- 2. output partials: out[t] = h_new @ fc_w.T + fc_b ----
        {
            const int j2 = tid * 2;
            float2 h2  = *(const float2*)&h_s[j2];
            float2 w02 = *(const float2*)&fc_w[j2];
            float2 w12 = *(const float2*)&fc_w[Hsz + j2];
            float a0 = h2.x * w02.x + h2.y * w02.y;
            float a1 = h2.x * w12.x + h2.y * w12.y;
            #pragma unroll
            for (int o = 32; o > 0; o >>= 1) {
                a0 += __shfl_down(a0, o, 64);
                a1 += __shfl_down(a1, o, 64);
            }
            if (lane == 0) { ored[wave * 2] = a0; ored[wave * 2 + 1] = a1; }
        }

        // ---- 3. eager refresh of pairs whose column module just updated ----
        {
            const int P = (A + 1) * (A + 2) / 2;
            for (int k = wave; k < P; k += NWAVES) {
                int r, c; pair_rc(k, r, c);
                refresh_pair(r, c);
            }
        }
        __syncthreads();

        // ---- 4. store the two outputs for this step ----
        if (tid == 0) {
            float o0 = fc_b[0], o1 = fc_b[1];
            #pragma unroll
            for (int w = 0; w < NWAVES; ++w) {
                o0 += ored[w * 2];
                o1 += ored[w * 2 + 1];
            }
            outb[t * 2]     = o0;
            outb[t * 2 + 1] = o1;
        }
        // no extra sync needed: ored is rewritten only after the next
        // step's phase-1 barrier, which thread 0 must also pass.
    }
}

// ---------------------------------------------------------------------------
extern "C" void kernel_launch(void* const* d_in, const int* in_sizes, int n_in,
                              void* d_out, int out_size, void* d_ws, size_t ws_size,
                              hipStream_t stream) {
    const float* x     = (const float*)d_in[0];
    const float* W_ih  = (const float*)d_in[1];
    const float* W_hh  = (const float*)d_in[2];
    const float* fc_w  = (const float*)d_in[3];
    const float* fc_b  = (const float*)d_in[4];
    const float* enc_w = (const float*)d_in[5];
    float* outp = (float*)d_out;
    float* WT   = (float*)d_ws;            // 1024*1024 floats = 4 MB

    dim3 tb(32, 8);
    dim3 tg(Hsz / 32, Hsz / 32);
    transpose_whh<<<tg, tb, 0, stream>>>(W_hh, WT);

    cwrnn_kernel<<<Bsz, NTHREADS, 0, stream>>>(x, W_ih, fc_w, fc_b, enc_w, WT, outp);
}

// Round 2
// 2591.194 us; speedup vs baseline: 1.1508x; 1.1508x over previous
//
#include <hip/hip_runtime.h>
#include <math.h>

#define Bsz 128
#define Tsz 512
#define Hsz 1024
#define NM  8
#define MS  128
#define NT  512

// ---------------------------------------------------------------------------
// Transpose W_hh (1024x1024) into workspace: WT[j*H + i] = W[i*H + j]
// ---------------------------------------------------------------------------
__global__ __launch_bounds__(256)
void transpose_whh(const float* __restrict__ W, float* __restrict__ WT) {
    __shared__ float tile[32][33];
    const int bx = blockIdx.x * 32;
    const int by = blockIdx.y * 32;
    const int tx = threadIdx.x;
    const int ty = threadIdx.y;
    #pragma unroll
    for (int k = 0; k < 32; k += 8)
        tile[ty + k][tx] = W[(size_t)(by + ty + k) * Hsz + bx + tx];
    __syncthreads();
    #pragma unroll
    for (int k = 0; k < 32; k += 8)
        WT[(size_t)(bx + ty + k) * Hsz + by + tx] = tile[tx][ty + k];
}

__device__ __forceinline__ float dot8(const float4* w, const float4* h) {
    float a = 0.f;
    #pragma unroll
    for (int u = 0; u < 8; ++u)
        a += w[u].x * h[u].x + w[u].y * h[u].y + w[u].z * h[u].z + w[u].w * h[u].w;
    return a;
}

// ---------------------------------------------------------------------------
// Persistent per-batch-element Clockwork RNN kernel. grid=128, block=512.
// Thread layout for refresh: row = tid&127 (output row in block),
//                            jc  = tid>>7  (j-chunk of 32 in reduction dim).
// S is stored as 4 partials per (pair,row): Sp[p][row*4+jc]; summed for free
// during the next step's float4 read in phase 1.
// Weight blocks (r,c) for c<=2 live in registers (192 VGPRs/thread).
// ---------------------------------------------------------------------------
__global__ __launch_bounds__(NT)
void cwrnn_kernel(const float* __restrict__ x,      // [B, T+1, 2, 1]
                  const float* __restrict__ W_ih,   // [H, 2]
                  const float* __restrict__ fc_w,   // [2, H]
                  const float* __restrict__ fc_b,   // [2]
                  const float* __restrict__ enc_w,  // [H, 2]
                  const float* __restrict__ WT,     // [H, H] transposed W_hh
                  float* __restrict__ out)          // [B, T, 2]
{
    __shared__ float h_s[Hsz];
    __shared__ float Sp[36][MS * 4];      // 73728 B, pairs column-major tri
    __shared__ float x_s[(Tsz + 1) * 2];
    __shared__ float wih_s[Hsz * 2];
    __shared__ float fcw_s[2 * Hsz];
    __shared__ float out_s[Tsz * 2];
    __shared__ float ored[8 * 2];

    const int tid  = threadIdx.x;
    const int lane = tid & 63;
    const int wave = tid >> 6;
    const int row  = tid & (MS - 1);
    const int jc   = tid >> 7;            // 0..3
    const int b    = blockIdx.x;

    const float* xb = x + (size_t)b * (Tsz + 1) * 2;

    // ---- one-time preloads into LDS ----
    for (int i = tid; i < (Tsz + 1) * 2; i += NT) x_s[i] = xb[i];
    for (int i = tid; i < Hsz * 2; i += NT) wih_s[i] = W_ih[i];
    for (int i = tid; i < 2 * Hsz; i += NT) fcw_s[i] = fc_w[i];
    const float fb0 = fc_b[0], fb1 = fc_b[1];

    // ---- register weight cache: p=0:(0,0) 1:(0,1) 2:(1,1) 3:(0,2) 4:(1,2) 5:(2,2)
    float4 wr[6][8];
    {
        const int pr[6] = {0, 0, 1, 0, 1, 2};
        const int pc[6] = {0, 1, 1, 2, 2, 2};
        #pragma unroll
        for (int p = 0; p < 6; ++p) {
            const float* wp = WT + (size_t)(pc[p] * MS + jc * 32) * Hsz + pr[p] * MS + row;
            #pragma unroll
            for (int u = 0; u < 8; ++u) {
                wr[p][u].x = wp[(size_t)(4 * u + 0) * Hsz];
                wr[p][u].y = wp[(size_t)(4 * u + 1) * Hsz];
                wr[p][u].z = wp[(size_t)(4 * u + 2) * Hsz];
                wr[p][u].w = wp[(size_t)(4 * u + 3) * Hsz];
            }
        }
    }

    // ---- h0 = x[:,0] @ enc_w.T ----
    {
        const float x00 = xb[0], x01 = xb[1];
        for (int i = tid; i < Hsz; i += NT)
            h_s[i] = x00 * enc_w[i * 2] + x01 * enc_w[i * 2 + 1];
    }
    __syncthreads();

    auto load_hcol = [&](int c, float4* hv) {
        const float4* hp = (const float4*)(h_s + c * MS + jc * 32);
        #pragma unroll
        for (int u = 0; u < 8; ++u) hv[u] = hp[u];   // wave-broadcast reads
    };

    // refresh all pairs in columns 0..A (module c just updated)
    auto refresh = [&](int A) {
        const int sidx = row * 4 + jc;
        float4 hv[8];
        load_hcol(0, hv);
        Sp[0][sidx] = dot8(wr[0], hv);
        if (A >= 1) {
            load_hcol(1, hv);
            Sp[1][sidx] = dot8(wr[1], hv);
            Sp[2][sidx] = dot8(wr[2], hv);
        }
        if (A >= 2) {
            load_hcol(2, hv);
            Sp[3][sidx] = dot8(wr[3], hv);
            Sp[4][sidx] = dot8(wr[4], hv);
            Sp[5][sidx] = dot8(wr[5], hv);
        }
        if (A >= 3) {
            for (int c = 3; c <= A; ++c) {
                load_hcol(c, hv);
                const int pb = c * (c + 1) / 2;
                for (int r = 0; r <= c; ++r) {
                    const float* wp = WT + (size_t)(c * MS + jc * 32) * Hsz + r * MS + row;
                    float a = 0.f;
                    #pragma unroll
                    for (int u = 0; u < 8; ++u) {
                        a += wp[(size_t)(4 * u + 0) * Hsz] * hv[u].x;
                        a += wp[(size_t)(4 * u + 1) * Hsz] * hv[u].y;
                        a += wp[(size_t)(4 * u + 2) * Hsz] * hv[u].z;
                        a += wp[(size_t)(4 * u + 3) * Hsz] * hv[u].w;
                    }
                    Sp[pb + r][sidx] = a;
                }
            }
        }
    };

    refresh(7);                 // initial S from h0 (all 36 pairs)
    __syncthreads();

    for (int t = 0; t < Tsz; ++t) {
        const int A = (t == 0) ? 7 : min(__ffs(t) - 1, 7);
        const int nrows = (A + 1) * MS;
        const float xt0 = x_s[(t + 1) * 2];
        const float xt1 = x_s[(t + 1) * 2 + 1];

        // ---- P1: candidate + h update for active rows ----
        for (int g = tid; g < nrows; g += NT) {
            const int r = g >> 7, il = g & (MS - 1);
            float pre = xt0 * wih_s[g * 2] + xt1 * wih_s[g * 2 + 1];
            for (int c = r; c < NM; ++c) {
                const float4 v = *(const float4*)&Sp[c * (c + 1) / 2 + r][il * 4];
                pre += (v.x + v.y) + (v.z + v.w);
            }
            h_s[g] = tanhf(pre);
        }
        __syncthreads();

        // ---- P2: out[t] = h @ fc_w.T + fc_b (partials per wave) ----
        {
            const int j2 = tid * 2;
            float2 h2 = *(const float2*)&h_s[j2];
            float2 w0 = *(const float2*)&fcw_s[j2];
            float2 w1 = *(const float2*)&fcw_s[Hsz + j2];
            float a0 = h2.x * w0.x + h2.y * w0.y;
            float a1 = h2.x * w1.x + h2.y * w1.y;
            #pragma unroll
            for (int o = 32; o > 0; o >>= 1) {
                a0 += __shfl_down(a0, o, 64);
                a1 += __shfl_down(a1, o, 64);
            }
            if (lane == 0) { ored[wave * 2] = a0; ored[wave * 2 + 1] = a1; }
        }

        // ---- P3: eager refresh of columns whose module just updated ----
        refresh(A);
        __syncthreads();

        // ---- P4: stage the step's 2 outputs in LDS ----
        if (tid == 0) {
            float o0 = fb0, o1 = fb1;
            #pragma unroll
            for (int w = 0; w < 8; ++w) { o0 += ored[w * 2]; o1 += ored[w * 2 + 1]; }
            out_s[t * 2]     = o0;
            out_s[t * 2 + 1] = o1;
        }
        // ored WAR hazard: next write happens after next step's barrier1,
        // which thread 0 must also reach. Safe.
    }

    __syncthreads();
    float* outb = out + (size_t)b * Tsz * 2;
    for (int i = tid; i < Tsz * 2; i += NT) outb[i] = out_s[i];
}

// ---------------------------------------------------------------------------
extern "C" void kernel_launch(void* const* d_in, const int* in_sizes, int n_in,
                              void* d_out, int out_size, void* d_ws, size_t ws_size,
                              hipStream_t stream) {
    const float* x     = (const float*)d_in[0];
    const float* W_ih  = (const float*)d_in[1];
    const float* W_hh  = (const float*)d_in[2];
    const float* fc_w  = (const float*)d_in[3];
    const float* fc_b  = (const float*)d_in[4];
    const float* enc_w = (const float*)d_in[5];
    float* outp = (float*)d_out;
    float* WT   = (float*)d_ws;            // 4 MB

    dim3 tb(32, 8);
    dim3 tg(Hsz / 32, Hsz / 32);
    transpose_whh<<<tg, tb, 0, stream>>>(W_hh, WT);

    cwrnn_kernel<<<Bsz, NT, 0, stream>>>(x, W_ih, fc_w, fc_b, enc_w, WT, outp);
}